// Round 3
// baseline (724.844 us; speedup 1.0000x reference)
//
#include <hip/hip_runtime.h>
#include <hip/hip_bf16.h>

#define NBATCH 2
#define NBB    16
#define NIC    8
#define NOC    16
#define NQ     30
#define NMM    6
#define NU     5
#define NV     5
#define NNC    25   // NU*NV

__global__ __launch_bounds__(256) void lbc_main(
    const float* __restrict__ x_re,   const float* __restrict__ x_im,
    const float* __restrict__ lnAlpha,const float* __restrict__ Phi,
    const float* __restrict__ lnTau,  const float* __restrict__ Psi,
    const float* __restrict__ pAlpha_re, const float* __restrict__ pAlpha_im,
    const float* __restrict__ pPhi_re,   const float* __restrict__ pPhi_im,
    const float* __restrict__ pTau_re,   const float* __restrict__ pTau_im,
    const float* __restrict__ pPsi_re,   const float* __restrict__ pPsi_im,
    const float* __restrict__ F_re,      const float* __restrict__ F_im,
    const float* __restrict__ coeffs,
    float* __restrict__ out)
{
    // ---- Build W = collect_weights(coeffs) into LDS: [c][n][o], complex ----
    __shared__ float Wre[NIC][NNC][NOC];
    __shared__ float Wim[NIC][NNC][NOC];
    for (int idx = threadIdx.x; idx < NIC * NNC * NOC; idx += 256) {
        int o = idx & (NOC - 1);
        int n = (idx / NOC) % NNC;
        int c = idx / (NOC * NNC);
        float wr, wi;
        if (n < 12) {
            wr = coeffs[(c * NNC + (23 - 2 * n)) * NOC + o];
            wi = coeffs[(c * NNC + (24 - 2 * n)) * NOC + o];
        } else if (n == 12) {
            wr = coeffs[(c * NNC + 0) * NOC + o];
            wi = 0.0f;
        } else {
            wr = coeffs[(c * NNC + (2 * n - 25)) * NOC + o];
            wi = coeffs[(c * NNC + (2 * n - 24)) * NOC + o];
        }
        Wre[c][n][o] = wr;
        Wim[c][n][o] = wi;
    }
    __syncthreads();

    // ---- Point identity ----
    const int bid = blockIdx.x;                 // 0..359
    const int m   = bid % NMM;
    const int q   = (bid / NMM) % NQ;
    const int b   = bid / (NMM * NQ);
    const int tid = threadIdx.x;
    const int y   = tid >> 4;
    const int x   = tid & 15;

    // ---- Block-uniform basis parameters (scalarized by compiler) ----
    const int qm = q * NMM + m;
    const float pAre = pAlpha_re[qm], pAim = pAlpha_im[qm];
    const float pPre = pPhi_re[m],    pPim = pPhi_im[m];
    float pTre[NU], pTim[NU], pSre[NV], pSim[NV];
    #pragma unroll
    for (int u = 0; u < NU; ++u) { pTre[u] = pTau_re[qm * NU + u]; pTim[u] = pTau_im[qm * NU + u]; }
    #pragma unroll
    for (int v = 0; v < NV; ++v) { pSre[v] = pPsi_re[m * NV + v]; pSim[v] = pPsi_im[m * NV + v]; }
    float Fr[NU][NV], Fi[NU][NV];
    #pragma unroll
    for (int u = 0; u < NU; ++u)
        #pragma unroll
        for (int v = 0; v < NV; ++v) {
            int fi = (qm * NU + u) * NV + v;
            Fr[u][v] = F_re[fi];
            Fi[u][v] = F_im[fi];
        }

    // ---- Per-point inputs (coalesced: 32B/lane per array) ----
    const int pbase = ((b * NBB + y) * NBB + x) * NIC;

    float accr[NOC], acci[NOC];
    #pragma unroll
    for (int o = 0; o < NOC; ++o) { accr[o] = 0.0f; acci[o] = 0.0f; }

    #pragma unroll
    for (int c = 0; c < NIC; ++c) {
        const float xr = x_re[pbase + c], xi = x_im[pbase + c];
        const float la = lnAlpha[pbase + c], ph = Phi[pbase + c];
        const float lt = lnTau[pbase + c],   ps = Psi[pbase + c];

        // A = x * exp(la*pAlpha + ph*pPhi)
        const float ar = la * pAre + ph * pPre;
        const float ai = la * pAim + ph * pPim;
        const float ea = __expf(ar);
        float sa, ca;
        __sincosf(ai, &sa, &ca);
        const float er_ = ea * ca, ei_ = ea * sa;
        const float Are = xr * er_ - xi * ei_;
        const float Aim = xr * ei_ + xi * er_;

        // eu[u] = exp(lt * pTau[u]),  ev[v] = exp(ps * pPsi[v])
        float eur[NU], eui[NU], evr[NV], evi[NV];
        #pragma unroll
        for (int u = 0; u < NU; ++u) {
            const float rr = __expf(lt * pTre[u]);
            float s, cc;
            __sincosf(lt * pTim[u], &s, &cc);
            eur[u] = rr * cc; eui[u] = rr * s;
        }
        #pragma unroll
        for (int v = 0; v < NV; ++v) {
            const float rr = __expf(ps * pSre[v]);
            float s, cc;
            __sincosf(ps * pSim[v], &s, &cc);
            evr[v] = rr * cc; evi[v] = rr * s;
        }

        #pragma unroll
        for (int u = 0; u < NU; ++u) {
            // g = A * eu[u]
            const float gr = Are * eur[u] - Aim * eui[u];
            const float gi = Are * eui[u] + Aim * eur[u];
            #pragma unroll
            for (int v = 0; v < NV; ++v) {
                // h = ev[v] * F[u][v];  t = g * h
                const float hr = evr[v] * Fr[u][v] - evi[v] * Fi[u][v];
                const float hi = evr[v] * Fi[u][v] + evi[v] * Fr[u][v];
                const float tr = gr * hr - gi * hi;
                const float ti = gr * hi + gi * hr;
                const int n = u * NV + v;
                #pragma unroll
                for (int o = 0; o < NOC; ++o) {
                    const float wr = Wre[c][n][o];
                    const float wi = Wim[c][n][o];
                    accr[o] += tr * wr - ti * wi;
                    acci[o] += tr * wi + ti * wr;
                }
            }
        }
    }

    // ---- Write out: [b, o, q, m, y, x, 2], float2 per (point,o) ----
    #pragma unroll
    for (int o = 0; o < NOC; ++o) {
        const size_t oi = (((((size_t)b * NOC + o) * NQ + q) * NMM + m) * NBB + y) * NBB + x;
        reinterpret_cast<float2*>(out)[oi] = make_float2(accr[o], acci[o]);
    }
}

extern "C" void kernel_launch(void* const* d_in, const int* in_sizes, int n_in,
                              void* d_out, int out_size, void* d_ws, size_t ws_size,
                              hipStream_t stream) {
    const float* x_re      = (const float*)d_in[0];
    const float* x_im      = (const float*)d_in[1];
    const float* lnAlpha   = (const float*)d_in[2];
    const float* Phi       = (const float*)d_in[3];
    const float* lnTau     = (const float*)d_in[4];
    const float* Psi       = (const float*)d_in[5];
    const float* pAlpha_re = (const float*)d_in[6];
    const float* pAlpha_im = (const float*)d_in[7];
    const float* pPhi_re   = (const float*)d_in[8];
    const float* pPhi_im   = (const float*)d_in[9];
    const float* pTau_re   = (const float*)d_in[10];
    const float* pTau_im   = (const float*)d_in[11];
    const float* pPsi_re   = (const float*)d_in[12];
    const float* pPsi_im   = (const float*)d_in[13];
    const float* F_re      = (const float*)d_in[14];
    const float* F_im      = (const float*)d_in[15];
    const float* coeffs    = (const float*)d_in[16];
    float* out = (float*)d_out;

    dim3 grid(NBATCH * NQ * NMM);   // 360
    dim3 block(256);                // (y,x) = 16x16
    lbc_main<<<grid, block, 0, stream>>>(
        x_re, x_im, lnAlpha, Phi, lnTau, Psi,
        pAlpha_re, pAlpha_im, pPhi_re, pPhi_im,
        pTau_re, pTau_im, pPsi_re, pPsi_im,
        F_re, F_im, coeffs, out);
}

// Round 4
// 404.174 us; speedup vs baseline: 1.7934x; 1.7934x over previous
//
#include <hip/hip_runtime.h>
#include <hip/hip_bf16.h>

#define NBATCH 2
#define NBB    16
#define NIC    8
#define NOC    16
#define NQ     30
#define NMM    6
#define NU     5
#define NV     5
#define NNC    25   // NU*NV
#define OGR    4    // o-groups per block (wave-uniform)
#define OPG    4    // o's per group  (OGR*OPG == NOC)

__global__ __launch_bounds__(256, 4) void lbc_main(
    const float* __restrict__ x_re,   const float* __restrict__ x_im,
    const float* __restrict__ lnAlpha,const float* __restrict__ Phi,
    const float* __restrict__ lnTau,  const float* __restrict__ Psi,
    const float* __restrict__ pAlpha_re, const float* __restrict__ pAlpha_im,
    const float* __restrict__ pPhi_re,   const float* __restrict__ pPhi_im,
    const float* __restrict__ pTau_re,   const float* __restrict__ pTau_im,
    const float* __restrict__ pPsi_re,   const float* __restrict__ pPsi_im,
    const float* __restrict__ F_re,      const float* __restrict__ F_im,
    const float* __restrict__ coeffs,
    float* __restrict__ out)
{
    // Block identity: bid = ((b*NQ + q)*NMM + m)*4 + qt
    const int bid = blockIdx.x;
    const int qt  = bid & 3;                 // y-quarter of the 16x16 tile
    const int bqm = bid >> 2;
    const int m   = bqm % NMM;
    const int q   = (bqm / NMM) % NQ;
    const int b   = bqm / (NMM * NQ);
    const int qm  = q * NMM + m;

    // ---- Stage W' = collect_weights(coeffs) * F[qm]  into LDS (float2) ----
    __shared__ float2 Wp[NIC][NNC][NOC];     // 25.6 KiB
    for (int idx = threadIdx.x; idx < NIC * NNC * NOC; idx += 256) {
        const int o = idx & (NOC - 1);
        const int n = (idx >> 4) % NNC;
        const int c = idx / (NOC * NNC);
        float wr, wi;
        if (n < 12) {
            wr = coeffs[(c * NNC + (23 - 2 * n)) * NOC + o];
            wi = coeffs[(c * NNC + (24 - 2 * n)) * NOC + o];
        } else if (n == 12) {
            wr = coeffs[(c * NNC + 0) * NOC + o];
            wi = 0.0f;
        } else {
            wr = coeffs[(c * NNC + (2 * n - 25)) * NOC + o];
            wi = coeffs[(c * NNC + (2 * n - 24)) * NOC + o];
        }
        const float fr = F_re[qm * NNC + n];
        const float fi = F_im[qm * NNC + n];
        Wp[c][n][o] = make_float2(wr * fr - wi * fi, wr * fi + wi * fr);
    }
    __syncthreads();

    // ---- Thread identity: og wave-uniform, p = point within quarter-tile ----
    const int tid = threadIdx.x;
    const int og  = tid >> 6;                // 0..3 (uniform per wave)
    const int p   = tid & 63;
    const int y   = qt * 4 + (p >> 4);
    const int x   = p & 15;

    // ---- Block-uniform basis parameters (uniform addresses -> scalar loads) ----
    const float pAre = pAlpha_re[qm], pAim = pAlpha_im[qm];
    const float pPre = pPhi_re[m],    pPim = pPhi_im[m];
    float pTre[NU], pTim[NU], pSre[NV], pSim[NV];
    #pragma unroll
    for (int u = 0; u < NU; ++u) { pTre[u] = pTau_re[qm * NU + u]; pTim[u] = pTau_im[qm * NU + u]; }
    #pragma unroll
    for (int v = 0; v < NV; ++v) { pSre[v] = pPsi_re[m * NV + v]; pSim[v] = pPsi_im[m * NV + v]; }

    const int pbase = ((b * NBB + y) * NBB + x) * NIC;

    float accr[OPG], acci[OPG];
    #pragma unroll
    for (int oo = 0; oo < OPG; ++oo) { accr[oo] = 0.0f; acci[oo] = 0.0f; }

    #pragma unroll 1
    for (int c = 0; c < NIC; ++c) {
        const float xr = x_re[pbase + c], xi = x_im[pbase + c];
        const float la = lnAlpha[pbase + c], ph = Phi[pbase + c];
        const float lt = lnTau[pbase + c],   ps = Psi[pbase + c];

        // A = x * exp(la*pAlpha + ph*pPhi)
        const float ar = la * pAre + ph * pPre;
        const float ai = la * pAim + ph * pPim;
        const float ea = __expf(ar);
        float sa, ca;
        __sincosf(ai, &sa, &ca);
        const float er_ = ea * ca, ei_ = ea * sa;
        const float Are = xr * er_ - xi * ei_;
        const float Aim = xr * ei_ + xi * er_;

        // eu[u] = exp(lt * pTau[u]),  ev[v] = exp(ps * pPsi[v])
        float eur[NU], eui[NU], evr[NV], evi[NV];
        #pragma unroll
        for (int u = 0; u < NU; ++u) {
            const float rr = __expf(lt * pTre[u]);
            float s, cc;
            __sincosf(lt * pTim[u], &s, &cc);
            eur[u] = rr * cc; eui[u] = rr * s;
        }
        #pragma unroll
        for (int v = 0; v < NV; ++v) {
            const float rr = __expf(ps * pSre[v]);
            float s, cc;
            __sincosf(ps * pSim[v], &s, &cc);
            evr[v] = rr * cc; evi[v] = rr * s;
        }

        #pragma unroll
        for (int u = 0; u < NU; ++u) {
            // g = A * eu[u]
            const float gr = Are * eur[u] - Aim * eui[u];
            const float gi = Are * eui[u] + Aim * eur[u];
            #pragma unroll
            for (int v = 0; v < NV; ++v) {
                // t = g * ev[v]   (F already folded into Wp)
                const float tr = gr * evr[v] - gi * evi[v];
                const float ti = gr * evi[v] + gi * evr[v];
                const int n = u * NV + v;
                #pragma unroll
                for (int oo = 0; oo < OPG; ++oo) {
                    const float2 w = Wp[c][n][og * OPG + oo];   // ds_read_b64 broadcast
                    accr[oo] += tr * w.x - ti * w.y;
                    acci[oo] += tr * w.y + ti * w.x;
                }
            }
        }
    }

    // ---- Write out: [b, o, q, m, y, x, 2] ----
    #pragma unroll
    for (int oo = 0; oo < OPG; ++oo) {
        const int o = og * OPG + oo;
        const size_t oi = (((((size_t)b * NOC + o) * NQ + q) * NMM + m) * NBB + y) * NBB + x;
        reinterpret_cast<float2*>(out)[oi] = make_float2(accr[oo], acci[oo]);
    }
}

extern "C" void kernel_launch(void* const* d_in, const int* in_sizes, int n_in,
                              void* d_out, int out_size, void* d_ws, size_t ws_size,
                              hipStream_t stream) {
    const float* x_re      = (const float*)d_in[0];
    const float* x_im      = (const float*)d_in[1];
    const float* lnAlpha   = (const float*)d_in[2];
    const float* Phi       = (const float*)d_in[3];
    const float* lnTau     = (const float*)d_in[4];
    const float* Psi       = (const float*)d_in[5];
    const float* pAlpha_re = (const float*)d_in[6];
    const float* pAlpha_im = (const float*)d_in[7];
    const float* pPhi_re   = (const float*)d_in[8];
    const float* pPhi_im   = (const float*)d_in[9];
    const float* pTau_re   = (const float*)d_in[10];
    const float* pTau_im   = (const float*)d_in[11];
    const float* pPsi_re   = (const float*)d_in[12];
    const float* pPsi_im   = (const float*)d_in[13];
    const float* F_re      = (const float*)d_in[14];
    const float* F_im      = (const float*)d_in[15];
    const float* coeffs    = (const float*)d_in[16];
    float* out = (float*)d_out;

    dim3 grid(NBATCH * NQ * NMM * 4);   // 1440
    dim3 block(256);                    // 4 o-groups x 64 points
    lbc_main<<<grid, block, 0, stream>>>(
        x_re, x_im, lnAlpha, Phi, lnTau, Psi,
        pAlpha_re, pAlpha_im, pPhi_re, pPhi_im,
        pTau_re, pTau_im, pPsi_re, pPsi_im,
        F_re, F_im, coeffs, out);
}